// Round 5
// baseline (719.478 us; speedup 1.0000x reference)
//
#include <hip/hip_runtime.h>
#include <math.h>

// Problem constants
constexpr int kN  = 50000;     // nodes
constexpr int kE  = 600000;    // raw edges
constexpr int kET = 650000;    // edges + self loops
constexpr int kG  = 50;        // graphs
constexpr int kH  = 4;         // heads

// ws layout (float-slot offsets)
constexpr size_t OFF_HCUR   = 0;           // N*64 bf16  -> 1.6M float slots
constexpr size_t OFF_HNEXT  = 1600000;     // N*64 f32   -> 3.2M
constexpr size_t OFF_Z      = 4800000;     // N*256 bf16 -> 6.4M slots
constexpr size_t OFF_ES     = 11200000;    // N*4 f32
constexpr size_t OFF_ED     = 11400000;    // N*4 f32
constexpr size_t OFF_ALPHA  = 11600000;    // ET*4 f32
constexpr size_t OFF_ROWPTR = 14200000;    // (N+1) ints
constexpr size_t OFF_CURSOR = 14260000;    // N ints
constexpr size_t OFF_SRC    = 14320000;    // ET ints
constexpr size_t OFF_WT2    = 14970000;    // 64*256 bf16 -> 8192 slots
constexpr size_t OFF_AHAT   = 14980000;    // 512 f32 (as[4][64], ad[4][64])
constexpr size_t OFF_BN     = 14990000;    // 2*64 f32
constexpr size_t OFF_PART   = 15000000;    // 64 ints

constexpr int kScanBlocks = (kN + 1023) / 1024;  // 49

typedef __bf16 bf16x8 __attribute__((ext_vector_type(8)));
typedef float  f32x4  __attribute__((ext_vector_type(4)));

__device__ inline ushort f2b(float f) {  // RNE float->bf16 bits
    unsigned u = __float_as_uint(f);
    return (ushort)((u + 0x7FFFu + ((u >> 16) & 1u)) >> 16);
}
__device__ inline float b2f(ushort u) {
    return __uint_as_float(((unsigned)u) << 16);
}

__device__ inline void edge_pair(const int* __restrict__ ei, int e, int& src, int& dst) {
    if (e < kE) { src = ei[e]; dst = ei[kE + e]; }
    else        { src = e - kE; dst = e - kE; }
}

// ---------------- CSR build (once per launch) ----------------
__global__ void k_hist(const int* __restrict__ ei, int* __restrict__ counts) {
    int e = blockIdx.x * blockDim.x + threadIdx.x;
    if (e >= kET) return;
    int src, dst;
    edge_pair(ei, e, src, dst);
    atomicAdd(&counts[dst], 1);
}

__global__ void __launch_bounds__(1024) k_scan_local(const int* __restrict__ counts,
                                                     int* __restrict__ rowptr,
                                                     int* __restrict__ partials) {
    int tid = threadIdx.x;
    int idx = blockIdx.x * 1024 + tid;
    int val = (idx < kN) ? counts[idx] : 0;
    int lane = tid & 63, w = tid >> 6;
    int x = val;
#pragma unroll
    for (int off = 1; off < 64; off <<= 1) {
        int t = __shfl_up(x, off);
        if (lane >= off) x += t;
    }
    __shared__ int wsum[16];
    if (lane == 63) wsum[w] = x;
    __syncthreads();
    if (w == 0 && lane < 16) {
        int y = wsum[lane];
#pragma unroll
        for (int off = 1; off < 16; off <<= 1) {
            int t = __shfl_up(y, off);
            if (lane >= off) y += t;
        }
        wsum[lane] = y;
    }
    __syncthreads();
    int incl = x + (w > 0 ? wsum[w - 1] : 0);
    if (idx < kN) rowptr[idx + 1] = incl;
    if (tid == 1023) partials[blockIdx.x] = incl;
}

__global__ void k_scan_part(int* __restrict__ partials) {
    int lane = threadIdx.x;
    int v = (lane < kScanBlocks) ? partials[lane] : 0;
    int x = v;
#pragma unroll
    for (int off = 1; off < 64; off <<= 1) {
        int t = __shfl_up(x, off);
        if (lane >= off) x += t;
    }
    if (lane < kScanBlocks) partials[lane] = x - v;
}

__global__ void __launch_bounds__(1024) k_scan_add(int* __restrict__ cursor,
                                                   int* __restrict__ rowptr,
                                                   const int* __restrict__ partials) {
    int idx = blockIdx.x * 1024 + threadIdx.x;
    if (idx >= kN) return;
    int incl = rowptr[idx + 1] + partials[blockIdx.x];
    rowptr[idx + 1] = incl;
    int val = cursor[idx];
    cursor[idx] = incl - val;
    if (idx == 0) rowptr[0] = 0;
}

__global__ void k_scatter(const int* __restrict__ ei, int* __restrict__ cursor,
                          int* __restrict__ src_csr) {
    int e = blockIdx.x * blockDim.x + threadIdx.x;
    if (e >= kET) return;
    int src, dst;
    edge_pair(ei, e, src, dst);
    int pos = atomicAdd(&cursor[dst], 1);
    src_csr[pos] = src;
}

// ---------------- encoder: h0 = x @ enc_w + enc_b (bf16 out) ----------------
__global__ void k_encoder(const float* __restrict__ x, const float* __restrict__ w,
                          const float* __restrict__ b, ushort* __restrict__ h) {
    int i = blockIdx.x * blockDim.x + threadIdx.x;
    if (i >= kN * 64) return;
    int n = i >> 6, c = i & 63;
    float acc = b[c];
#pragma unroll
    for (int k = 0; k < 5; ++k) acc += x[n * 5 + k] * w[k * 64 + c];
    h[i] = f2b(acc);
}

// ahat_{s,d}[h][k] = sum_c W[k, h*dout+c] * a_{s,d}[h][c]   (ahat: [2][4][64] f32)
__global__ void k_ahat(const float* __restrict__ W, const float* __restrict__ a_s,
                       const float* __restrict__ a_d, float* __restrict__ ahat, int dout) {
    int i = threadIdx.x;
    if (i >= 256) return;
    int h = i >> 6, k = i & 63;
    int HD = 4 * dout;
    const float* wr = W + (size_t)k * HD + h * dout;
    float s1 = 0.f, s2 = 0.f;
    for (int c = 0; c < dout; ++c) {
        float w = wr[c];
        s1 += w * a_s[h * dout + c];
        s2 += w * a_d[h * dout + c];
    }
    ahat[i] = s1;
    ahat[256 + i] = s2;
}

// es[n][0..3], ed[n][0..3] = h[n][:64] . ahat rows  (one thread per node)
__global__ void k_att2(const ushort* __restrict__ h, const float* __restrict__ ahat,
                       float* __restrict__ es, float* __restrict__ ed) {
    int n = blockIdx.x * blockDim.x + threadIdx.x;
    if (n >= kN) return;
    const uint4* row = reinterpret_cast<const uint4*>(h + (size_t)n * 64);
    float e_s[4] = {0.f, 0.f, 0.f, 0.f};
    float e_d[4] = {0.f, 0.f, 0.f, 0.f};
#pragma unroll
    for (int c8 = 0; c8 < 8; ++c8) {
        uint4 v = row[c8];
        unsigned uu[4] = {v.x, v.y, v.z, v.w};
#pragma unroll
        for (int q = 0; q < 4; ++q) {
            float lo = __uint_as_float(uu[q] << 16);
            float hi = __uint_as_float(uu[q] & 0xFFFF0000u);
            int k = c8 * 8 + q * 2;
#pragma unroll
            for (int hh = 0; hh < 4; ++hh) {
                e_s[hh] += lo * ahat[hh * 64 + k] + hi * ahat[hh * 64 + k + 1];
                e_d[hh] += lo * ahat[256 + hh * 64 + k] + hi * ahat[256 + hh * 64 + k + 1];
            }
        }
    }
    ((float4*)es)[n] = make_float4(e_s[0], e_s[1], e_s[2], e_s[3]);
    ((float4*)ed)[n] = make_float4(e_d[0], e_d[1], e_d[2], e_d[3]);
}

// per-(dst,head): pass1 scores cached into alpha + online max/sum; pass2 normalize
__global__ void k_softmax(const int* __restrict__ rowptr, const int* __restrict__ src_csr,
                          const float* __restrict__ es, const float* __restrict__ ed,
                          float* __restrict__ alpha) {
    int i = blockIdx.x * blockDim.x + threadIdx.x;
    if (i >= kN * kH) return;
    int dst = i >> 2, h = i & 3;
    int start = rowptr[dst], end = rowptr[dst + 1];
    float edv = ed[i];
    float m = -INFINITY, s = 0.f;
    for (int pos = start; pos < end; ++pos) {
        int src = src_csr[pos];
        float v = es[src * 4 + h] + edv;
        v = (v >= 0.f) ? v : 0.2f * v;
        alpha[pos * 4 + h] = v;
        float nm = fmaxf(m, v);
        s = s * __expf(m - nm) + __expf(v - nm);
        m = nm;
    }
    float inv = 0.25f / (s + 1e-16f);
    for (int pos = start; pos < end; ++pos) {
        float v = alpha[pos * 4 + h];
        alpha[pos * 4 + h] = __expf(v - m) * inv;
    }
}

// one wave per dst; lane = input channel k. z[dst][h*64+k] = sum_e alpha[e,h]*h[src][k]
__global__ void __launch_bounds__(256) k_agg2(const int* __restrict__ rowptr,
                                              const int* __restrict__ src_csr,
                                              const float* __restrict__ alpha,
                                              const ushort* __restrict__ h,
                                              ushort* __restrict__ z) {
    int wid = threadIdx.x >> 6;
    int lane = threadIdx.x & 63;
    int dst = blockIdx.x * 4 + wid;
    if (dst >= kN) return;
    int start = rowptr[dst], end = rowptr[dst + 1];
    const float4* al4 = (const float4*)alpha;

    float a0 = 0.f, a1 = 0.f, a2 = 0.f, a3 = 0.f;
    for (int pos = start; pos < end; ++pos) {
        int src = src_csr[pos];
        float4 w = al4[pos];
        float f = b2f(h[(size_t)src * 64 + lane]);
        a0 += w.x * f;
        a1 += w.y * f;
        a2 += w.z * f;
        a3 += w.w * f;
    }
    ushort* zr = z + (size_t)dst * 256 + lane;
    zr[0]   = f2b(a0);
    zr[64]  = f2b(a1);
    zr[128] = f2b(a2);
    zr[192] = f2b(a3);
}

// W[64][4*dout] f32 -> Wt2[dout][256] bf16, Wt2[c][h*64+k] = W[k][h*dout+c]
__global__ void k_wt2(const float* __restrict__ W, ushort* __restrict__ Wt2, int dout) {
    int i = blockIdx.x * blockDim.x + threadIdx.x;
    if (i >= dout * 256) return;
    int c = i >> 8, kk = i & 255;
    int h = kk >> 6, k = kk & 63;
    Wt2[i] = f2b(W[(size_t)k * (4 * dout) + h * dout + c]);
}

// MFMA GEMM: hnext[N][DOUT] = Z[N][256] @ Wt2^T, f32 out. One wave = 16x16 tile, 8 MFMAs.
template <int DOUT>
__global__ void __launch_bounds__(256) k_zgemm(const ushort* __restrict__ z,
                                               const ushort* __restrict__ Wt2,
                                               float* __restrict__ hnext) {
    constexpr int NT = DOUT / 16;
    int wave = (blockIdx.x * blockDim.x + threadIdx.x) >> 6;
    int lane = threadIdx.x & 63;
    int mtile = wave / NT;
    int ntile = wave - mtile * NT;
    if (mtile >= kN / 16) return;
    int m0 = mtile * 16;
    int n0 = ntile * 16;

    int row = lane & 15;
    int k0  = (lane >> 4) * 8;

    const ushort* za = z + (size_t)(m0 + row) * 256 + k0;
    const ushort* wb = Wt2 + (size_t)(n0 + row) * 256 + k0;

    f32x4 acc = {0.f, 0.f, 0.f, 0.f};
#pragma unroll
    for (int ks = 0; ks < 8; ++ks) {
        bf16x8 a = *reinterpret_cast<const bf16x8*>(za + ks * 32);
        bf16x8 b = *reinterpret_cast<const bf16x8*>(wb + ks * 32);
        acc = __builtin_amdgcn_mfma_f32_16x16x32_bf16(a, b, acc, 0, 0, 0);
    }

    int col = lane & 15;
    int r0  = (lane >> 4) * 4;
#pragma unroll
    for (int r = 0; r < 4; ++r) {
        hnext[(size_t)(m0 + r0 + r) * DOUT + n0 + col] = acc[r];
    }
}

// per-channel sum and sumsq over nodes
template <int DOUT>
__global__ void k_bn_stats(const float* __restrict__ h, float* __restrict__ bn) {
    constexpr int ROWS = 256 / DOUT;
    __shared__ float ls[256], lq[256];
    int c = threadIdx.x % DOUT;
    int r = threadIdx.x / DOUT;
    float s = 0.f, q = 0.f;
    for (int n = blockIdx.x * ROWS + r; n < kN; n += gridDim.x * ROWS) {
        float v = h[n * DOUT + c];
        s += v;
        q += v * v;
    }
    ls[threadIdx.x] = s;
    lq[threadIdx.x] = q;
    __syncthreads();
    if (r == 0) {
#pragma unroll
        for (int i = 1; i < ROWS; ++i) {
            s += ls[i * DOUT + c];
            q += lq[i * DOUT + c];
        }
        atomicAdd(&bn[c], s);
        atomicAdd(&bn[DOUT + c], q);
    }
}

template <int DOUT, bool RELU, bool BF16OUT>
__global__ void k_bn_apply(const float* __restrict__ h, const float* __restrict__ bn,
                           const float* __restrict__ g, const float* __restrict__ be,
                           void* __restrict__ outp) {
    int i = blockIdx.x * blockDim.x + threadIdx.x;
    if (i >= kN * DOUT) return;
    int c = i % DOUT;
    float mu = bn[c] * (1.f / kN);
    float var = bn[DOUT + c] * (1.f / kN) - mu * mu;
    float v = g[c] * (h[i] - mu) * rsqrtf(var + 1e-5f) + be[c];
    if (RELU) v = fmaxf(v, 0.f);
    if (BF16OUT) ((ushort*)outp)[i] = f2b(v);
    else         ((float*)outp)[i] = v;
}

// per-graph pooling
__global__ void k_pool(const float* __restrict__ h, const int* __restrict__ batch,
                       float* __restrict__ gemb) {
    int g = blockIdx.x;
    int lo = 0, hi = kN;
    while (lo < hi) { int mid = (lo + hi) >> 1; if (batch[mid] < g) lo = mid + 1; else hi = mid; }
    int start = lo;
    lo = start; hi = kN;
    while (lo < hi) { int mid = (lo + hi) >> 1; if (batch[mid] < g + 1) lo = mid + 1; else hi = mid; }
    int end = lo;

    int c = threadIdx.x & 31, r = threadIdx.x >> 5;
    float sum = 0.f, mx = -INFINITY;
    for (int n = start + r; n < end; n += 8) {
        float v = h[n * 32 + c];
        sum += v;
        mx = fmaxf(mx, v);
    }
    __shared__ float ssum[256], smax[256];
    ssum[threadIdx.x] = sum;
    smax[threadIdx.x] = mx;
    __syncthreads();
    if (r == 0) {
#pragma unroll
        for (int i = 1; i < 8; ++i) {
            sum += ssum[i * 32 + c];
            mx = fmaxf(mx, smax[i * 32 + c]);
        }
        int cnt = end - start;
        float mean = sum / fmaxf((float)cnt, 1.f);
        if (cnt <= 0) mx = 0.f;
        gemb[g * 32 + c] = (mean + mx + sum) * (1.f / 3.f);
    }
}

__global__ void k_heads(const float* __restrict__ gemb, const float* __restrict__ ew1,
                        const float* __restrict__ eb1, const float* __restrict__ ew2,
                        const float* __restrict__ eb2, const float* __restrict__ mw1,
                        const float* __restrict__ mb1, const float* __restrict__ mw2,
                        const float* __restrict__ mb2, float* __restrict__ eth,
                        float* __restrict__ man) {
    int g = blockIdx.x * blockDim.x + threadIdx.x;
    if (g >= kG) return;
    const float* row = gemb + g * 32;
    float acc_e = eb2[0], acc_m = mb2[0];
#pragma unroll 4
    for (int j = 0; j < 16; ++j) {
        float he = eb1[j], hm = mb1[j];
        for (int k = 0; k < 32; ++k) {
            float v = row[k];
            he += v * ew1[k * 16 + j];
            hm += v * mw1[k * 16 + j];
        }
        acc_e += fmaxf(he, 0.f) * ew2[j];
        acc_m += fmaxf(hm, 0.f) * mw2[j];
    }
    eth[g] = 1.f / (1.f + expf(-acc_e));
    man[g] = 1.f / (1.f + expf(-acc_m));
}

extern "C" void kernel_launch(void* const* d_in, const int* in_sizes, int n_in,
                              void* d_out, int out_size, void* d_ws, size_t ws_size,
                              hipStream_t stream) {
    const float* x     = (const float*)d_in[0];
    const int*   ei    = (const int*)d_in[1];
    const int*   batch = (const int*)d_in[2];
    const float* enc_w = (const float*)d_in[3];
    const float* enc_b = (const float*)d_in[4];

    float* ws = (float*)d_ws;
    ushort* hcur  = (ushort*)(ws + OFF_HCUR);
    float*  hnext = ws + OFF_HNEXT;
    ushort* z     = (ushort*)(ws + OFF_Z);
    float*  es    = ws + OFF_ES;
    float*  ed    = ws + OFF_ED;
    float*  alpha = ws + OFF_ALPHA;
    int*    rowptr= (int*)(ws + OFF_ROWPTR);
    int*    cursor= (int*)(ws + OFF_CURSOR);
    int*    srcc  = (int*)(ws + OFF_SRC);
    ushort* Wt2   = (ushort*)(ws + OFF_WT2);
    float*  ahat  = ws + OFF_AHAT;
    float*  bn    = ws + OFF_BN;
    int*    part  = (int*)(ws + OFF_PART);

    float* out      = (float*)d_out;
    float* out_h    = out;                 // N*32
    float* out_gemb = out + 1600000;       // G*32
    float* out_eth  = out + 1601600;       // G
    float* out_man  = out + 1601650;       // G

    // ---- CSR build (once) ----
    hipMemsetAsync(cursor, 0, kN * sizeof(int), stream);
    k_hist<<<(kET + 255) / 256, 256, 0, stream>>>(ei, cursor);
    k_scan_local<<<kScanBlocks, 1024, 0, stream>>>(cursor, rowptr, part);
    k_scan_part<<<1, 64, 0, stream>>>(part);
    k_scan_add<<<kScanBlocks, 1024, 0, stream>>>(cursor, rowptr, part);
    k_scatter<<<(kET + 255) / 256, 256, 0, stream>>>(ei, cursor, srcc);

    k_encoder<<<(kN * 64 + 255) / 256, 256, 0, stream>>>(x, enc_w, enc_b, hcur);

    for (int l = 0; l < 3; ++l) {
        const int dout = (l == 2) ? 32 : 64;
        const float* W   = (const float*)d_in[5 + 6 * l];
        const float* a_s = (const float*)d_in[6 + 6 * l];
        const float* a_d = (const float*)d_in[7 + 6 * l];
        const float* gam = (const float*)d_in[9 + 6 * l];
        const float* bet = (const float*)d_in[10 + 6 * l];

        k_ahat<<<1, 256, 0, stream>>>(W, a_s, a_d, ahat, dout);
        k_att2<<<(kN + 255) / 256, 256, 0, stream>>>(hcur, ahat, es, ed);
        k_softmax<<<(kN * kH + 255) / 256, 256, 0, stream>>>(rowptr, srcc, es, ed, alpha);
        k_agg2<<<kN / 4, 256, 0, stream>>>(rowptr, srcc, alpha, hcur, z);
        k_wt2<<<(dout * 256 + 255) / 256, 256, 0, stream>>>(W, Wt2, dout);

        hipMemsetAsync(bn, 0, 2 * 64 * sizeof(float), stream);

        if (dout == 64) {
            k_zgemm<64><<<3125, 256, 0, stream>>>(z, Wt2, hnext);
            k_bn_stats<64><<<128, 256, 0, stream>>>(hnext, bn);
            if (l < 2)
                k_bn_apply<64, true, true><<<(kN * 64 + 255) / 256, 256, 0, stream>>>(hnext, bn, gam, bet, hcur);
            else
                k_bn_apply<64, false, true><<<(kN * 64 + 255) / 256, 256, 0, stream>>>(hnext, bn, gam, bet, hcur);
        } else {
            k_zgemm<32><<<1563, 256, 0, stream>>>(z, Wt2, hnext);
            k_bn_stats<32><<<128, 256, 0, stream>>>(hnext, bn);
            k_bn_apply<32, false, false><<<(kN * 32 + 255) / 256, 256, 0, stream>>>(hnext, bn, gam, bet, out_h);
        }
    }

    k_pool<<<kG, 256, 0, stream>>>(out_h, batch, out_gemb);

    k_heads<<<1, 64, 0, stream>>>(out_gemb,
                                  (const float*)d_in[23], (const float*)d_in[24],
                                  (const float*)d_in[25], (const float*)d_in[26],
                                  (const float*)d_in[27], (const float*)d_in[28],
                                  (const float*)d_in[29], (const float*)d_in[30],
                                  out_eth, out_man);
}

// Round 6
// 591.319 us; speedup vs baseline: 1.2167x; 1.2167x over previous
//
#include <hip/hip_runtime.h>
#include <math.h>

// Problem constants
constexpr int kN  = 50000;     // nodes
constexpr int kE  = 600000;    // raw edges
constexpr int kET = 650000;    // edges + self loops
constexpr int kG  = 50;        // graphs
constexpr int kH  = 4;         // heads

// ws layout (float-slot offsets)
constexpr size_t OFF_HCUR   = 0;           // N*64 bf16  -> 1.6M float slots
constexpr size_t OFF_HNEXT  = 1600000;     // N*64 f32   -> 3.2M
constexpr size_t OFF_Z      = 4800000;     // N*256 bf16 -> 6.4M slots
constexpr size_t OFF_ES     = 11200000;    // N*4 f32
constexpr size_t OFF_ED     = 11400000;    // N*4 f32
constexpr size_t OFF_ROWPTR = 14200000;    // (N+1) ints
constexpr size_t OFF_CURSOR = 14260000;    // N ints
constexpr size_t OFF_SRC    = 14320000;    // ET ints
constexpr size_t OFF_WT2    = 14970000;    // 64*256 bf16 -> 8192 slots
constexpr size_t OFF_AHAT   = 14980000;    // 512 f32 (as[4][64], ad[4][64])
constexpr size_t OFF_BN     = 14990000;    // 2*64 f32
constexpr size_t OFF_PART   = 15000000;    // 64 ints

constexpr int kScanBlocks = (kN + 1023) / 1024;  // 49

typedef __bf16 bf16x8 __attribute__((ext_vector_type(8)));
typedef float  f32x4  __attribute__((ext_vector_type(4)));

__device__ inline ushort f2b(float f) {  // RNE float->bf16 bits
    unsigned u = __float_as_uint(f);
    return (ushort)((u + 0x7FFFu + ((u >> 16) & 1u)) >> 16);
}
__device__ inline float b2f(ushort u) {
    return __uint_as_float(((unsigned)u) << 16);
}

__device__ inline void edge_pair(const int* __restrict__ ei, int e, int& src, int& dst) {
    if (e < kE) { src = ei[e]; dst = ei[kE + e]; }
    else        { src = e - kE; dst = e - kE; }
}

// ---------------- CSR build (once per launch) ----------------
__global__ void k_hist(const int* __restrict__ ei, int* __restrict__ counts) {
    int e = blockIdx.x * blockDim.x + threadIdx.x;
    if (e >= kET) return;
    int src, dst;
    edge_pair(ei, e, src, dst);
    atomicAdd(&counts[dst], 1);
}

__global__ void __launch_bounds__(1024) k_scan_local(const int* __restrict__ counts,
                                                     int* __restrict__ rowptr,
                                                     int* __restrict__ partials) {
    int tid = threadIdx.x;
    int idx = blockIdx.x * 1024 + tid;
    int val = (idx < kN) ? counts[idx] : 0;
    int lane = tid & 63, w = tid >> 6;
    int x = val;
#pragma unroll
    for (int off = 1; off < 64; off <<= 1) {
        int t = __shfl_up(x, off);
        if (lane >= off) x += t;
    }
    __shared__ int wsum[16];
    if (lane == 63) wsum[w] = x;
    __syncthreads();
    if (w == 0 && lane < 16) {
        int y = wsum[lane];
#pragma unroll
        for (int off = 1; off < 16; off <<= 1) {
            int t = __shfl_up(y, off);
            if (lane >= off) y += t;
        }
        wsum[lane] = y;
    }
    __syncthreads();
    int incl = x + (w > 0 ? wsum[w - 1] : 0);
    if (idx < kN) rowptr[idx + 1] = incl;
    if (tid == 1023) partials[blockIdx.x] = incl;
}

__global__ void k_scan_part(int* __restrict__ partials) {
    int lane = threadIdx.x;
    int v = (lane < kScanBlocks) ? partials[lane] : 0;
    int x = v;
#pragma unroll
    for (int off = 1; off < 64; off <<= 1) {
        int t = __shfl_up(x, off);
        if (lane >= off) x += t;
    }
    if (lane < kScanBlocks) partials[lane] = x - v;
}

__global__ void __launch_bounds__(1024) k_scan_add(int* __restrict__ cursor,
                                                   int* __restrict__ rowptr,
                                                   const int* __restrict__ partials) {
    int idx = blockIdx.x * 1024 + threadIdx.x;
    if (idx >= kN) return;
    int incl = rowptr[idx + 1] + partials[blockIdx.x];
    rowptr[idx + 1] = incl;
    int val = cursor[idx];
    cursor[idx] = incl - val;
    if (idx == 0) rowptr[0] = 0;
}

__global__ void k_scatter(const int* __restrict__ ei, int* __restrict__ cursor,
                          int* __restrict__ src_csr) {
    int e = blockIdx.x * blockDim.x + threadIdx.x;
    if (e >= kET) return;
    int src, dst;
    edge_pair(ei, e, src, dst);
    int pos = atomicAdd(&cursor[dst], 1);
    src_csr[pos] = src;
}

// ---------------- encoder: h0 = x @ enc_w + enc_b (bf16 out) ----------------
__global__ void k_encoder(const float* __restrict__ x, const float* __restrict__ w,
                          const float* __restrict__ b, ushort* __restrict__ h) {
    int i = blockIdx.x * blockDim.x + threadIdx.x;
    if (i >= kN * 64) return;
    int n = i >> 6, c = i & 63;
    float acc = b[c];
#pragma unroll
    for (int k = 0; k < 5; ++k) acc += x[n * 5 + k] * w[k * 64 + c];
    h[i] = f2b(acc);
}

// merged weight prep: block 0 -> ahat; blocks 1.. -> Wt2
// ahat_{s,d}[h][k] = sum_c W[k, h*dout+c] * a_{s,d}[h][c]
// Wt2[c][h*64+k] = W[k][h*dout+c] (bf16)
__global__ void k_prep(const float* __restrict__ W, const float* __restrict__ a_s,
                       const float* __restrict__ a_d, float* __restrict__ ahat,
                       ushort* __restrict__ Wt2, int dout) {
    if (blockIdx.x == 0) {
        int i = threadIdx.x;
        int h = i >> 6, k = i & 63;
        int HD = 4 * dout;
        const float* wr = W + (size_t)k * HD + h * dout;
        float s1 = 0.f, s2 = 0.f;
        for (int c = 0; c < dout; ++c) {
            float w = wr[c];
            s1 += w * a_s[h * dout + c];
            s2 += w * a_d[h * dout + c];
        }
        ahat[i] = s1;
        ahat[256 + i] = s2;
    } else {
        int i = (blockIdx.x - 1) * 256 + threadIdx.x;
        if (i >= dout * 256) return;
        int c = i >> 8, kk = i & 255;
        int h = kk >> 6, k = kk & 63;
        Wt2[i] = f2b(W[(size_t)k * (4 * dout) + h * dout + c]);
    }
}

// es[n][0..3], ed[n][0..3] = h[n][:64] . ahat rows  (one thread per node)
__global__ void k_att2(const ushort* __restrict__ h, const float* __restrict__ ahat,
                       float* __restrict__ es, float* __restrict__ ed) {
    int n = blockIdx.x * blockDim.x + threadIdx.x;
    if (n >= kN) return;
    const uint4* row = reinterpret_cast<const uint4*>(h + (size_t)n * 64);
    float e_s[4] = {0.f, 0.f, 0.f, 0.f};
    float e_d[4] = {0.f, 0.f, 0.f, 0.f};
#pragma unroll
    for (int c8 = 0; c8 < 8; ++c8) {
        uint4 v = row[c8];
        unsigned uu[4] = {v.x, v.y, v.z, v.w};
#pragma unroll
        for (int q = 0; q < 4; ++q) {
            float lo = __uint_as_float(uu[q] << 16);
            float hi = __uint_as_float(uu[q] & 0xFFFF0000u);
            int k = c8 * 8 + q * 2;
#pragma unroll
            for (int hh = 0; hh < 4; ++hh) {
                e_s[hh] += lo * ahat[hh * 64 + k] + hi * ahat[hh * 64 + k + 1];
                e_d[hh] += lo * ahat[256 + hh * 64 + k] + hi * ahat[256 + hh * 64 + k + 1];
            }
        }
    }
    ((float4*)es)[n] = make_float4(e_s[0], e_s[1], e_s[2], e_s[3]);
    ((float4*)ed)[n] = make_float4(e_d[0], e_d[1], e_d[2], e_d[3]);
}

// Fused edge-softmax + aggregation. One wave per dst.
// Phase 1 (16 edges/chunk): lane = e_l*4+h scores; online max/sum via shfl_xor.
// Phase 2: lane = q*16+c4; 4 edges in flight; gather h[src] 4ch/lane via uint2;
// flash-style acc rescale; final cross-q reduce + normalized bf16 store.
__global__ void __launch_bounds__(256) k_gat(const int* __restrict__ rowptr,
                                             const int* __restrict__ srcc,
                                             const float* __restrict__ es,
                                             const float* __restrict__ ed,
                                             const ushort* __restrict__ h,
                                             ushort* __restrict__ z) {
    int wid = threadIdx.x >> 6;
    int lane = threadIdx.x & 63;
    int dst = blockIdx.x * 4 + wid;   // kN % 4 == 0
    int start = rowptr[dst], end = rowptr[dst + 1];

    int e_l = lane >> 2, hh = lane & 3;    // phase-1 mapping
    int q = lane >> 4, c4 = lane & 15;     // phase-2 mapping

    float edv = ed[dst * 4 + hh];
    float m = -3e38f, s = 0.f;
    float acc[4][4] = {};

    for (int cs = start; cs < end; cs += 16) {
        // ---- phase 1: scores for up to 16 edges ----
        int pos = cs + e_l;
        float v = -3e38f;
        if (pos < end) {
            int src = srcc[pos];
            v = es[src * 4 + hh] + edv;
            v = (v >= 0.f) ? v : 0.2f * v;
        }
        float cm = v;
        cm = fmaxf(cm, __shfl_xor(cm, 4));
        cm = fmaxf(cm, __shfl_xor(cm, 8));
        cm = fmaxf(cm, __shfl_xor(cm, 16));
        cm = fmaxf(cm, __shfl_xor(cm, 32));
        float mn = fmaxf(m, cm);
        float scale = __expf(m - mn);
        float p = __expf(v - mn);          // 0 for invalid lanes
        float cth = p;
        cth += __shfl_xor(cth, 4);
        cth += __shfl_xor(cth, 8);
        cth += __shfl_xor(cth, 16);
        cth += __shfl_xor(cth, 32);
        s = s * scale + cth;
        m = mn;

        // rescale accumulators (per-head scale broadcast from lanes 0..3)
        float sc0 = __shfl(scale, 0), sc1 = __shfl(scale, 1);
        float sc2 = __shfl(scale, 2), sc3 = __shfl(scale, 3);
#pragma unroll
        for (int c = 0; c < 4; ++c) {
            acc[0][c] *= sc0; acc[1][c] *= sc1; acc[2][c] *= sc2; acc[3][c] *= sc3;
        }

        // ---- phase 2: weighted gather, 4 edges in flight ----
#pragma unroll
        for (int t = 0; t < 4; ++t) {
            int el = t * 4 + q;
            int pos2 = cs + el;
            float p0 = __shfl(p, (el << 2) | 0);
            float p1 = __shfl(p, (el << 2) | 1);
            float p2 = __shfl(p, (el << 2) | 2);
            float p3 = __shfl(p, (el << 2) | 3);
            if (pos2 < end) {
                int src = srcc[pos2];
                uint2 hv = *reinterpret_cast<const uint2*>(h + (size_t)src * 64 + c4 * 4);
                float c0 = __uint_as_float(hv.x << 16);
                float c1 = __uint_as_float(hv.x & 0xFFFF0000u);
                float c2 = __uint_as_float(hv.y << 16);
                float c3 = __uint_as_float(hv.y & 0xFFFF0000u);
                acc[0][0] += p0 * c0; acc[0][1] += p0 * c1; acc[0][2] += p0 * c2; acc[0][3] += p0 * c3;
                acc[1][0] += p1 * c0; acc[1][1] += p1 * c1; acc[1][2] += p1 * c2; acc[1][3] += p1 * c3;
                acc[2][0] += p2 * c0; acc[2][1] += p2 * c1; acc[2][2] += p2 * c2; acc[2][3] += p2 * c3;
                acc[3][0] += p3 * c0; acc[3][1] += p3 * c1; acc[3][2] += p3 * c2; acc[3][3] += p3 * c3;
            }
        }
    }

    // normalize (0.25/s per head) and reduce across q groups
    float myinv = 0.25f / (s + 1e-16f);
    float inv0 = __shfl(myinv, 0), inv1 = __shfl(myinv, 1);
    float inv2 = __shfl(myinv, 2), inv3 = __shfl(myinv, 3);
#pragma unroll
    for (int c = 0; c < 4; ++c) {
        acc[0][c] *= inv0; acc[1][c] *= inv1; acc[2][c] *= inv2; acc[3][c] *= inv3;
    }
#pragma unroll
    for (int j = 0; j < 4; ++j) {
#pragma unroll
        for (int c = 0; c < 4; ++c) {
            float v = acc[j][c];
            v += __shfl_xor(v, 16);
            v += __shfl_xor(v, 32);
            acc[j][c] = v;
        }
    }
    if (q == 0) {
        ushort* zr = z + (size_t)dst * 256 + c4 * 4;
#pragma unroll
        for (int j = 0; j < 4; ++j) {
            ushort4 o;
            o.x = f2b(acc[j][0]); o.y = f2b(acc[j][1]);
            o.z = f2b(acc[j][2]); o.w = f2b(acc[j][3]);
            *reinterpret_cast<ushort4*>(zr + j * 64) = o;
        }
    }
}

// MFMA GEMM: hnext[N][DOUT] = Z[N][256] @ Wt2^T, f32 out. One wave = 16x16 tile, 8 MFMAs.
template <int DOUT>
__global__ void __launch_bounds__(256) k_zgemm(const ushort* __restrict__ z,
                                               const ushort* __restrict__ Wt2,
                                               float* __restrict__ hnext) {
    constexpr int NT = DOUT / 16;
    int wave = (blockIdx.x * blockDim.x + threadIdx.x) >> 6;
    int lane = threadIdx.x & 63;
    int mtile = wave / NT;
    int ntile = wave - mtile * NT;
    if (mtile >= kN / 16) return;
    int m0 = mtile * 16;
    int n0 = ntile * 16;

    int row = lane & 15;
    int k0  = (lane >> 4) * 8;

    const ushort* za = z + (size_t)(m0 + row) * 256 + k0;
    const ushort* wb = Wt2 + (size_t)(n0 + row) * 256 + k0;

    f32x4 acc = {0.f, 0.f, 0.f, 0.f};
#pragma unroll
    for (int ks = 0; ks < 8; ++ks) {
        bf16x8 a = *reinterpret_cast<const bf16x8*>(za + ks * 32);
        bf16x8 b = *reinterpret_cast<const bf16x8*>(wb + ks * 32);
        acc = __builtin_amdgcn_mfma_f32_16x16x32_bf16(a, b, acc, 0, 0, 0);
    }

    int col = lane & 15;
    int r0  = (lane >> 4) * 4;
#pragma unroll
    for (int r = 0; r < 4; ++r) {
        hnext[(size_t)(m0 + r0 + r) * DOUT + n0 + col] = acc[r];
    }
}

// per-channel sum and sumsq over nodes
template <int DOUT>
__global__ void k_bn_stats(const float* __restrict__ h, float* __restrict__ bn) {
    constexpr int ROWS = 256 / DOUT;
    __shared__ float ls[256], lq[256];
    int c = threadIdx.x % DOUT;
    int r = threadIdx.x / DOUT;
    float s = 0.f, q = 0.f;
    for (int n = blockIdx.x * ROWS + r; n < kN; n += gridDim.x * ROWS) {
        float v = h[n * DOUT + c];
        s += v;
        q += v * v;
    }
    ls[threadIdx.x] = s;
    lq[threadIdx.x] = q;
    __syncthreads();
    if (r == 0) {
#pragma unroll
        for (int i = 1; i < ROWS; ++i) {
            s += ls[i * DOUT + c];
            q += lq[i * DOUT + c];
        }
        atomicAdd(&bn[c], s);
        atomicAdd(&bn[DOUT + c], q);
    }
}

template <int DOUT, bool RELU, bool BF16OUT>
__global__ void k_bn_apply(const float* __restrict__ h, const float* __restrict__ bn,
                           const float* __restrict__ g, const float* __restrict__ be,
                           void* __restrict__ outp) {
    int i = blockIdx.x * blockDim.x + threadIdx.x;
    if (i >= kN * DOUT) return;
    int c = i % DOUT;
    float mu = bn[c] * (1.f / kN);
    float var = bn[DOUT + c] * (1.f / kN) - mu * mu;
    float v = g[c] * (h[i] - mu) * rsqrtf(var + 1e-5f) + be[c];
    if (RELU) v = fmaxf(v, 0.f);
    if (BF16OUT) ((ushort*)outp)[i] = f2b(v);
    else         ((float*)outp)[i] = v;
}

// per-graph pooling
__global__ void k_pool(const float* __restrict__ h, const int* __restrict__ batch,
                       float* __restrict__ gemb) {
    int g = blockIdx.x;
    int lo = 0, hi = kN;
    while (lo < hi) { int mid = (lo + hi) >> 1; if (batch[mid] < g) lo = mid + 1; else hi = mid; }
    int start = lo;
    lo = start; hi = kN;
    while (lo < hi) { int mid = (lo + hi) >> 1; if (batch[mid] < g + 1) lo = mid + 1; else hi = mid; }
    int end = lo;

    int c = threadIdx.x & 31, r = threadIdx.x >> 5;
    float sum = 0.f, mx = -INFINITY;
    for (int n = start + r; n < end; n += 8) {
        float v = h[n * 32 + c];
        sum += v;
        mx = fmaxf(mx, v);
    }
    __shared__ float ssum[256], smax[256];
    ssum[threadIdx.x] = sum;
    smax[threadIdx.x] = mx;
    __syncthreads();
    if (r == 0) {
#pragma unroll
        for (int i = 1; i < 8; ++i) {
            sum += ssum[i * 32 + c];
            mx = fmaxf(mx, smax[i * 32 + c]);
        }
        int cnt = end - start;
        float mean = sum / fmaxf((float)cnt, 1.f);
        if (cnt <= 0) mx = 0.f;
        gemb[g * 32 + c] = (mean + mx + sum) * (1.f / 3.f);
    }
}

__global__ void k_heads(const float* __restrict__ gemb, const float* __restrict__ ew1,
                        const float* __restrict__ eb1, const float* __restrict__ ew2,
                        const float* __restrict__ eb2, const float* __restrict__ mw1,
                        const float* __restrict__ mb1, const float* __restrict__ mw2,
                        const float* __restrict__ mb2, float* __restrict__ eth,
                        float* __restrict__ man) {
    int g = blockIdx.x * blockDim.x + threadIdx.x;
    if (g >= kG) return;
    const float* row = gemb + g * 32;
    float acc_e = eb2[0], acc_m = mb2[0];
#pragma unroll 4
    for (int j = 0; j < 16; ++j) {
        float he = eb1[j], hm = mb1[j];
        for (int k = 0; k < 32; ++k) {
            float v = row[k];
            he += v * ew1[k * 16 + j];
            hm += v * mw1[k * 16 + j];
        }
        acc_e += fmaxf(he, 0.f) * ew2[j];
        acc_m += fmaxf(hm, 0.f) * mw2[j];
    }
    eth[g] = 1.f / (1.f + expf(-acc_e));
    man[g] = 1.f / (1.f + expf(-acc_m));
}

extern "C" void kernel_launch(void* const* d_in, const int* in_sizes, int n_in,
                              void* d_out, int out_size, void* d_ws, size_t ws_size,
                              hipStream_t stream) {
    const float* x     = (const float*)d_in[0];
    const int*   ei    = (const int*)d_in[1];
    const int*   batch = (const int*)d_in[2];
    const float* enc_w = (const float*)d_in[3];
    const float* enc_b = (const float*)d_in[4];

    float* ws = (float*)d_ws;
    ushort* hcur  = (ushort*)(ws + OFF_HCUR);
    float*  hnext = ws + OFF_HNEXT;
    ushort* z     = (ushort*)(ws + OFF_Z);
    float*  es    = ws + OFF_ES;
    float*  ed    = ws + OFF_ED;
    int*    rowptr= (int*)(ws + OFF_ROWPTR);
    int*    cursor= (int*)(ws + OFF_CURSOR);
    int*    srcc  = (int*)(ws + OFF_SRC);
    ushort* Wt2   = (ushort*)(ws + OFF_WT2);
    float*  ahat  = ws + OFF_AHAT;
    float*  bn    = ws + OFF_BN;
    int*    part  = (int*)(ws + OFF_PART);

    float* out      = (float*)d_out;
    float* out_h    = out;                 // N*32
    float* out_gemb = out + 1600000;       // G*32
    float* out_eth  = out + 1601600;       // G
    float* out_man  = out + 1601650;       // G

    // ---- CSR build (once) ----
    hipMemsetAsync(cursor, 0, kN * sizeof(int), stream);
    k_hist<<<(kET + 255) / 256, 256, 0, stream>>>(ei, cursor);
    k_scan_local<<<kScanBlocks, 1024, 0, stream>>>(cursor, rowptr, part);
    k_scan_part<<<1, 64, 0, stream>>>(part);
    k_scan_add<<<kScanBlocks, 1024, 0, stream>>>(cursor, rowptr, part);
    k_scatter<<<(kET + 255) / 256, 256, 0, stream>>>(ei, cursor, srcc);

    k_encoder<<<(kN * 64 + 255) / 256, 256, 0, stream>>>(x, enc_w, enc_b, hcur);

    for (int l = 0; l < 3; ++l) {
        const int dout = (l == 2) ? 32 : 64;
        const float* W   = (const float*)d_in[5 + 6 * l];
        const float* a_s = (const float*)d_in[6 + 6 * l];
        const float* a_d = (const float*)d_in[7 + 6 * l];
        const float* gam = (const float*)d_in[9 + 6 * l];
        const float* bet = (const float*)d_in[10 + 6 * l];

        k_prep<<<1 + (dout * 256 + 255) / 256, 256, 0, stream>>>(W, a_s, a_d, ahat, Wt2, dout);
        k_att2<<<(kN + 255) / 256, 256, 0, stream>>>(hcur, ahat, es, ed);
        k_gat<<<kN / 4, 256, 0, stream>>>(rowptr, srcc, es, ed, hcur, z);

        hipMemsetAsync(bn, 0, 2 * 64 * sizeof(float), stream);

        if (dout == 64) {
            k_zgemm<64><<<3125, 256, 0, stream>>>(z, Wt2, hnext);
            k_bn_stats<64><<<128, 256, 0, stream>>>(hnext, bn);
            if (l < 2)
                k_bn_apply<64, true, true><<<(kN * 64 + 255) / 256, 256, 0, stream>>>(hnext, bn, gam, bet, hcur);
            else
                k_bn_apply<64, false, true><<<(kN * 64 + 255) / 256, 256, 0, stream>>>(hnext, bn, gam, bet, hcur);
        } else {
            k_zgemm<32><<<1563, 256, 0, stream>>>(z, Wt2, hnext);
            k_bn_stats<32><<<128, 256, 0, stream>>>(hnext, bn);
            k_bn_apply<32, false, false><<<(kN * 32 + 255) / 256, 256, 0, stream>>>(hnext, bn, gam, bet, out_h);
        }
    }

    k_pool<<<kG, 256, 0, stream>>>(out_h, batch, out_gemb);

    k_heads<<<1, 64, 0, stream>>>(out_gemb,
                                  (const float*)d_in[23], (const float*)d_in[24],
                                  (const float*)d_in[25], (const float*)d_in[26],
                                  (const float*)d_in[27], (const float*)d_in[28],
                                  (const float*)d_in[29], (const float*)d_in[30],
                                  out_eth, out_man);
}

// Round 7
// 572.052 us; speedup vs baseline: 1.2577x; 1.0337x over previous
//
#include <hip/hip_runtime.h>
#include <math.h>

// Problem constants
constexpr int kN  = 50000;     // nodes
constexpr int kE  = 600000;    // raw edges
constexpr int kET = 650000;    // edges + self loops
constexpr int kG  = 50;        // graphs
constexpr int kH  = 4;         // heads

// ws layout (float-slot offsets)
constexpr size_t OFF_HCUR   = 0;           // N*64 bf16  -> 1.6M float slots
constexpr size_t OFF_HNEXT  = 1600000;     // N*64 f32   -> 3.2M
constexpr size_t OFF_Z      = 4800000;     // N*256 bf16 -> 6.4M slots
constexpr size_t OFF_ES     = 11200000;    // N*4 f32
constexpr size_t OFF_ED     = 11400000;    // N*4 f32
constexpr size_t OFF_ROWPTR = 14200000;    // (N+1) ints
constexpr size_t OFF_CURSOR = 14260000;    // N ints
constexpr size_t OFF_SRC    = 14320000;    // ET ints
constexpr size_t OFF_WT2    = 14970000;    // 3 layers x 8192 slots (bf16 [dout][256])
constexpr size_t OFF_AHAT   = 15000000;    // 3 layers x 512 f32
constexpr size_t OFF_BN     = 15002000;    // 2*64 f32
constexpr size_t OFF_PART   = 15003000;    // 64 ints

constexpr int kScanBlocks = (kN + 1023) / 1024;  // 49

typedef __bf16 bf16x8 __attribute__((ext_vector_type(8)));
typedef float  f32x4  __attribute__((ext_vector_type(4)));

__device__ inline ushort f2b(float f) {  // RNE float->bf16 bits
    unsigned u = __float_as_uint(f);
    return (ushort)((u + 0x7FFFu + ((u >> 16) & 1u)) >> 16);
}
__device__ inline float b2f(ushort u) {
    return __uint_as_float(((unsigned)u) << 16);
}

__device__ inline void edge_pair(const int* __restrict__ ei, int e, int& src, int& dst) {
    if (e < kE) { src = ei[e]; dst = ei[kE + e]; }
    else        { src = e - kE; dst = e - kE; }
}

// ---------------- CSR build (once per launch) ----------------
__global__ void k_hist(const int* __restrict__ ei, int* __restrict__ counts) {
    int e = blockIdx.x * blockDim.x + threadIdx.x;
    if (e >= kET) return;
    int src, dst;
    edge_pair(ei, e, src, dst);
    atomicAdd(&counts[dst], 1);
}

__global__ void __launch_bounds__(1024) k_scan_local(const int* __restrict__ counts,
                                                     int* __restrict__ rowptr,
                                                     int* __restrict__ partials) {
    int tid = threadIdx.x;
    int idx = blockIdx.x * 1024 + tid;
    int val = (idx < kN) ? counts[idx] : 0;
    int lane = tid & 63, w = tid >> 6;
    int x = val;
#pragma unroll
    for (int off = 1; off < 64; off <<= 1) {
        int t = __shfl_up(x, off);
        if (lane >= off) x += t;
    }
    __shared__ int wsum[16];
    if (lane == 63) wsum[w] = x;
    __syncthreads();
    if (w == 0 && lane < 16) {
        int y = wsum[lane];
#pragma unroll
        for (int off = 1; off < 16; off <<= 1) {
            int t = __shfl_up(y, off);
            if (lane >= off) y += t;
        }
        wsum[lane] = y;
    }
    __syncthreads();
    int incl = x + (w > 0 ? wsum[w - 1] : 0);
    if (idx < kN) rowptr[idx + 1] = incl;
    if (tid == 1023) partials[blockIdx.x] = incl;
}

__global__ void k_scan_part(int* __restrict__ partials) {
    int lane = threadIdx.x;
    int v = (lane < kScanBlocks) ? partials[lane] : 0;
    int x = v;
#pragma unroll
    for (int off = 1; off < 64; off <<= 1) {
        int t = __shfl_up(x, off);
        if (lane >= off) x += t;
    }
    if (lane < kScanBlocks) partials[lane] = x - v;
}

__global__ void __launch_bounds__(1024) k_scan_add(int* __restrict__ cursor,
                                                   int* __restrict__ rowptr,
                                                   const int* __restrict__ partials) {
    int idx = blockIdx.x * 1024 + threadIdx.x;
    if (idx >= kN) return;
    int incl = rowptr[idx + 1] + partials[blockIdx.x];
    rowptr[idx + 1] = incl;
    int val = cursor[idx];
    cursor[idx] = incl - val;
    if (idx == 0) rowptr[0] = 0;
}

__global__ void k_scatter(const int* __restrict__ ei, int* __restrict__ cursor,
                          int* __restrict__ src_csr) {
    int e = blockIdx.x * blockDim.x + threadIdx.x;
    if (e >= kET) return;
    int src, dst;
    edge_pair(ei, e, src, dst);
    int pos = atomicAdd(&cursor[dst], 1);
    src_csr[pos] = src;
}

// ---------------- weight prep: all 3 layers in one dispatch ----------------
// ahat[l][{s,d}][h][k] = sum_c W_l[k, h*dout+c] * a_{s,d}[h][c]
// Wt2[l][c][h*64+k]    = W_l[k][h*dout+c]  (bf16)
__global__ void k_prep_all(const float* __restrict__ w0, const float* __restrict__ w1,
                           const float* __restrict__ w2, const float* __restrict__ as0,
                           const float* __restrict__ as1, const float* __restrict__ as2,
                           const float* __restrict__ ad0, const float* __restrict__ ad1,
                           const float* __restrict__ ad2, float* __restrict__ ahat,
                           ushort* __restrict__ Wt2) {
    int b = blockIdx.x;
    if (b < 3) {
        const float* W  = (b == 0) ? w0 : (b == 1) ? w1 : w2;
        const float* As = (b == 0) ? as0 : (b == 1) ? as1 : as2;
        const float* Ad = (b == 0) ? ad0 : (b == 1) ? ad1 : ad2;
        int dout = (b == 2) ? 32 : 64;
        int i = threadIdx.x;
        int h = i >> 6, k = i & 63;
        const float* wr = W + (size_t)k * (4 * dout) + h * dout;
        float s1 = 0.f, s2 = 0.f;
        for (int c = 0; c < dout; ++c) {
            float w = wr[c];
            s1 += w * As[h * dout + c];
            s2 += w * Ad[h * dout + c];
        }
        ahat[b * 512 + i] = s1;
        ahat[b * 512 + 256 + i] = s2;
    } else {
        int i = (b - 3) * 256 + threadIdx.x;   // over 2*16384 + 8192 = 40960
        if (i >= 40960) return;
        int l, li;
        if (i < 16384)      { l = 0; li = i; }
        else if (i < 32768) { l = 1; li = i - 16384; }
        else                { l = 2; li = i - 32768; }
        int dout = (l == 2) ? 32 : 64;
        const float* W = (l == 0) ? w0 : (l == 1) ? w1 : w2;
        int c = li >> 8, kk = li & 255;
        int h = kk >> 6, k = kk & 63;
        Wt2[l * 16384 + li] = f2b(W[(size_t)k * (4 * dout) + h * dout + c]);
    }
}

// ---------------- encoder + fused layer-0 es/ed ----------------
// wave = node, lane = channel
__global__ void __launch_bounds__(256) k_encoder_att(const float* __restrict__ x,
                                                     const float* __restrict__ w,
                                                     const float* __restrict__ b,
                                                     const float* __restrict__ ahat0,
                                                     ushort* __restrict__ h,
                                                     float* __restrict__ es,
                                                     float* __restrict__ ed) {
    int node = blockIdx.x * 4 + (threadIdx.x >> 6);
    int lane = threadIdx.x & 63;
    float acc = b[lane];
#pragma unroll
    for (int k = 0; k < 5; ++k) acc += x[node * 5 + k] * w[k * 64 + lane];
    h[(size_t)node * 64 + lane] = f2b(acc);

    float ps[4], pd[4];
#pragma unroll
    for (int hh = 0; hh < 4; ++hh) {
        ps[hh] = acc * ahat0[hh * 64 + lane];
        pd[hh] = acc * ahat0[256 + hh * 64 + lane];
    }
#pragma unroll
    for (int off = 1; off < 64; off <<= 1) {
#pragma unroll
        for (int hh = 0; hh < 4; ++hh) {
            ps[hh] += __shfl_xor(ps[hh], off);
            pd[hh] += __shfl_xor(pd[hh], off);
        }
    }
    if (lane == 0) {
        ((float4*)es)[node] = make_float4(ps[0], ps[1], ps[2], ps[3]);
        ((float4*)ed)[node] = make_float4(pd[0], pd[1], pd[2], pd[3]);
    }
}

// Fused edge-softmax + aggregation. One wave per dst.
// Fast path deg<=16: prefetch gathers before the softmax reduce, no rescale.
__global__ void __launch_bounds__(256) k_gat(const int* __restrict__ rowptr,
                                             const int* __restrict__ srcc,
                                             const float* __restrict__ es,
                                             const float* __restrict__ ed,
                                             const ushort* __restrict__ h,
                                             ushort* __restrict__ z) {
    int wid = threadIdx.x >> 6;
    int lane = threadIdx.x & 63;
    int dst = blockIdx.x * 4 + wid;   // kN % 4 == 0
    int start = rowptr[dst], end = rowptr[dst + 1];
    int deg = end - start;

    int e_l = lane >> 2, hh = lane & 3;    // score mapping
    int q = lane >> 4, c4 = lane & 15;     // gather mapping

    float edv = ed[dst * 4 + hh];
    float acc[4][4] = {};
    float s;

    if (deg <= 16) {
        // ---- scores ----
        int pos = start + e_l;
        int psafe = (pos < end) ? pos : start;
        int src = srcc[psafe];
        float v = es[src * 4 + hh] + edv;
        v = (v >= 0.f) ? v : 0.2f * v;
        if (pos >= end) v = -3e38f;

        // ---- prefetch gathers (independent of softmax chain) ----
        uint2 hv[4];
#pragma unroll
        for (int t = 0; t < 4; ++t) {
            int p2 = start + t * 4 + q;
            int p2s = (p2 < end) ? p2 : start;
            int s2 = srcc[p2s];
            hv[t] = *reinterpret_cast<const uint2*>(h + (size_t)s2 * 64 + c4 * 4);
        }

        // ---- softmax reduce ----
        float cm = v;
        cm = fmaxf(cm, __shfl_xor(cm, 4));
        cm = fmaxf(cm, __shfl_xor(cm, 8));
        cm = fmaxf(cm, __shfl_xor(cm, 16));
        cm = fmaxf(cm, __shfl_xor(cm, 32));
        float p = __expf(v - cm);            // 0 for padded lanes
        float cs = p;
        cs += __shfl_xor(cs, 4);
        cs += __shfl_xor(cs, 8);
        cs += __shfl_xor(cs, 16);
        cs += __shfl_xor(cs, 32);
        s = cs;

        // ---- weighted accumulate (p==0 kills padded edges) ----
#pragma unroll
        for (int t = 0; t < 4; ++t) {
            int el = t * 4 + q;
            float p0 = __shfl(p, (el << 2) | 0);
            float p1 = __shfl(p, (el << 2) | 1);
            float p2 = __shfl(p, (el << 2) | 2);
            float p3 = __shfl(p, (el << 2) | 3);
            float c0 = __uint_as_float(hv[t].x << 16);
            float c1 = __uint_as_float(hv[t].x & 0xFFFF0000u);
            float c2 = __uint_as_float(hv[t].y << 16);
            float c3 = __uint_as_float(hv[t].y & 0xFFFF0000u);
            acc[0][0] += p0 * c0; acc[0][1] += p0 * c1; acc[0][2] += p0 * c2; acc[0][3] += p0 * c3;
            acc[1][0] += p1 * c0; acc[1][1] += p1 * c1; acc[1][2] += p1 * c2; acc[1][3] += p1 * c3;
            acc[2][0] += p2 * c0; acc[2][1] += p2 * c1; acc[2][2] += p2 * c2; acc[2][3] += p2 * c3;
            acc[3][0] += p3 * c0; acc[3][1] += p3 * c1; acc[3][2] += p3 * c2; acc[3][3] += p3 * c3;
        }
    } else {
        // ---- general online-softmax path ----
        float m = -3e38f;
        s = 0.f;
        for (int cs0 = start; cs0 < end; cs0 += 16) {
            int pos = cs0 + e_l;
            int psafe = (pos < end) ? pos : start;
            int src = srcc[psafe];
            float v = es[src * 4 + hh] + edv;
            v = (v >= 0.f) ? v : 0.2f * v;
            if (pos >= end) v = -3e38f;

            float cm = v;
            cm = fmaxf(cm, __shfl_xor(cm, 4));
            cm = fmaxf(cm, __shfl_xor(cm, 8));
            cm = fmaxf(cm, __shfl_xor(cm, 16));
            cm = fmaxf(cm, __shfl_xor(cm, 32));
            float mn = fmaxf(m, cm);
            float scale = __expf(m - mn);
            float p = __expf(v - mn);
            float cth = p;
            cth += __shfl_xor(cth, 4);
            cth += __shfl_xor(cth, 8);
            cth += __shfl_xor(cth, 16);
            cth += __shfl_xor(cth, 32);
            s = s * scale + cth;
            m = mn;

            float sc0 = __shfl(scale, 0), sc1 = __shfl(scale, 1);
            float sc2 = __shfl(scale, 2), sc3 = __shfl(scale, 3);
#pragma unroll
            for (int c = 0; c < 4; ++c) {
                acc[0][c] *= sc0; acc[1][c] *= sc1; acc[2][c] *= sc2; acc[3][c] *= sc3;
            }
#pragma unroll
            for (int t = 0; t < 4; ++t) {
                int el = t * 4 + q;
                int p2 = cs0 + el;
                int p2s = (p2 < end) ? p2 : start;
                int s2 = srcc[p2s];
                uint2 hv = *reinterpret_cast<const uint2*>(h + (size_t)s2 * 64 + c4 * 4);
                float p0 = __shfl(p, (el << 2) | 0);
                float p1 = __shfl(p, (el << 2) | 1);
                float p2f = __shfl(p, (el << 2) | 2);
                float p3 = __shfl(p, (el << 2) | 3);
                float c0 = __uint_as_float(hv.x << 16);
                float c1 = __uint_as_float(hv.x & 0xFFFF0000u);
                float c2 = __uint_as_float(hv.y << 16);
                float c3 = __uint_as_float(hv.y & 0xFFFF0000u);
                acc[0][0] += p0 * c0;  acc[0][1] += p0 * c1;  acc[0][2] += p0 * c2;  acc[0][3] += p0 * c3;
                acc[1][0] += p1 * c0;  acc[1][1] += p1 * c1;  acc[1][2] += p1 * c2;  acc[1][3] += p1 * c3;
                acc[2][0] += p2f * c0; acc[2][1] += p2f * c1; acc[2][2] += p2f * c2; acc[2][3] += p2f * c3;
                acc[3][0] += p3 * c0;  acc[3][1] += p3 * c1;  acc[3][2] += p3 * c2;  acc[3][3] += p3 * c3;
            }
        }
    }

    // normalize (0.25/s per head) and reduce across q groups
    float myinv = 0.25f / (s + 1e-16f);
    float inv0 = __shfl(myinv, 0), inv1 = __shfl(myinv, 1);
    float inv2 = __shfl(myinv, 2), inv3 = __shfl(myinv, 3);
#pragma unroll
    for (int c = 0; c < 4; ++c) {
        acc[0][c] *= inv0; acc[1][c] *= inv1; acc[2][c] *= inv2; acc[3][c] *= inv3;
    }
#pragma unroll
    for (int j = 0; j < 4; ++j) {
#pragma unroll
        for (int c = 0; c < 4; ++c) {
            float v = acc[j][c];
            v += __shfl_xor(v, 16);
            v += __shfl_xor(v, 32);
            acc[j][c] = v;
        }
    }
    if (q == 0) {
        ushort* zr = z + (size_t)dst * 256 + c4 * 4;
#pragma unroll
        for (int j = 0; j < 4; ++j) {
            ushort4 o;
            o.x = f2b(acc[j][0]); o.y = f2b(acc[j][1]);
            o.z = f2b(acc[j][2]); o.w = f2b(acc[j][3]);
            *reinterpret_cast<ushort4*>(zr + j * 64) = o;
        }
    }
}

// MFMA GEMM with A-reuse: one wave computes a 16x32 tile (2 n-tiles), 16 MFMAs.
template <int DOUT>
__global__ void __launch_bounds__(256) k_zgemm(const ushort* __restrict__ z,
                                               const ushort* __restrict__ Wt2l,
                                               float* __restrict__ hnext) {
    constexpr int NG = DOUT / 32;
    int wid = (blockIdx.x * 256 + threadIdx.x) >> 6;
    int lane = threadIdx.x & 63;
    int mtile = wid / NG;
    int ng = wid - mtile * NG;
    if (mtile >= kN / 16) return;
    int m0 = mtile * 16;
    int n0 = ng * 32;

    int row = lane & 15;
    int k0  = (lane >> 4) * 8;

    const ushort* za = z + (size_t)(m0 + row) * 256 + k0;
    bf16x8 a[8];
#pragma unroll
    for (int ks = 0; ks < 8; ++ks)
        a[ks] = *reinterpret_cast<const bf16x8*>(za + ks * 32);

    const ushort* wb0 = Wt2l + (size_t)(n0 + row) * 256 + k0;
    const ushort* wb1 = wb0 + 16 * 256;
    f32x4 acc0 = {0.f, 0.f, 0.f, 0.f};
    f32x4 acc1 = {0.f, 0.f, 0.f, 0.f};
#pragma unroll
    for (int ks = 0; ks < 8; ++ks) {
        bf16x8 b0 = *reinterpret_cast<const bf16x8*>(wb0 + ks * 32);
        bf16x8 b1 = *reinterpret_cast<const bf16x8*>(wb1 + ks * 32);
        acc0 = __builtin_amdgcn_mfma_f32_16x16x32_bf16(a[ks], b0, acc0, 0, 0, 0);
        acc1 = __builtin_amdgcn_mfma_f32_16x16x32_bf16(a[ks], b1, acc1, 0, 0, 0);
    }

    int col = lane & 15;
    int r0  = (lane >> 4) * 4;
#pragma unroll
    for (int r = 0; r < 4; ++r) {
        hnext[(size_t)(m0 + r0 + r) * DOUT + n0 + col]      = acc0[r];
        hnext[(size_t)(m0 + r0 + r) * DOUT + n0 + 16 + col] = acc1[r];
    }
}

// per-channel sum and sumsq over nodes
template <int DOUT>
__global__ void k_bn_stats(const float* __restrict__ h, float* __restrict__ bn) {
    constexpr int ROWS = 256 / DOUT;
    __shared__ float ls[256], lq[256];
    int c = threadIdx.x % DOUT;
    int r = threadIdx.x / DOUT;
    float s = 0.f, q = 0.f;
    for (int n = blockIdx.x * ROWS + r; n < kN; n += gridDim.x * ROWS) {
        float v = h[n * DOUT + c];
        s += v;
        q += v * v;
    }
    ls[threadIdx.x] = s;
    lq[threadIdx.x] = q;
    __syncthreads();
    if (r == 0) {
#pragma unroll
        for (int i = 1; i < ROWS; ++i) {
            s += ls[i * DOUT + c];
            q += lq[i * DOUT + c];
        }
        atomicAdd(&bn[c], s);
        atomicAdd(&bn[DOUT + c], q);
    }
}

// BN apply (layers 0,1: dout=64, relu) fused with NEXT layer's es/ed
__global__ void __launch_bounds__(256) k_bn_apply_att(const float* __restrict__ hnext,
                                                      const float* __restrict__ bn,
                                                      const float* __restrict__ g,
                                                      const float* __restrict__ be,
                                                      const float* __restrict__ ahat_next,
                                                      ushort* __restrict__ hcur,
                                                      float* __restrict__ es,
                                                      float* __restrict__ ed) {
    int node = blockIdx.x * 4 + (threadIdx.x >> 6);
    int lane = threadIdx.x & 63;
    float mu = bn[lane] * (1.f / kN);
    float var = bn[64 + lane] * (1.f / kN) - mu * mu;
    float v = g[lane] * (hnext[(size_t)node * 64 + lane] - mu) * rsqrtf(var + 1e-5f) + be[lane];
    v = fmaxf(v, 0.f);
    hcur[(size_t)node * 64 + lane] = f2b(v);

    float ps[4], pd[4];
#pragma unroll
    for (int hh = 0; hh < 4; ++hh) {
        ps[hh] = v * ahat_next[hh * 64 + lane];
        pd[hh] = v * ahat_next[256 + hh * 64 + lane];
    }
#pragma unroll
    for (int off = 1; off < 64; off <<= 1) {
#pragma unroll
        for (int hh = 0; hh < 4; ++hh) {
            ps[hh] += __shfl_xor(ps[hh], off);
            pd[hh] += __shfl_xor(pd[hh], off);
        }
    }
    if (lane == 0) {
        ((float4*)es)[node] = make_float4(ps[0], ps[1], ps[2], ps[3]);
        ((float4*)ed)[node] = make_float4(pd[0], pd[1], pd[2], pd[3]);
    }
}

// final BN apply (layer 2, dout=32, f32 out, no relu)
__global__ void k_bn_apply32(const float* __restrict__ h, const float* __restrict__ bn,
                             const float* __restrict__ g, const float* __restrict__ be,
                             float* __restrict__ outp) {
    int i = blockIdx.x * blockDim.x + threadIdx.x;
    if (i >= kN * 32) return;
    int c = i & 31;
    float mu = bn[c] * (1.f / kN);
    float var = bn[32 + c] * (1.f / kN) - mu * mu;
    outp[i] = g[c] * (h[i] - mu) * rsqrtf(var + 1e-5f) + be[c];
}

// per-graph pooling
__global__ void k_pool(const float* __restrict__ h, const int* __restrict__ batch,
                       float* __restrict__ gemb) {
    int g = blockIdx.x;
    int lo = 0, hi = kN;
    while (lo < hi) { int mid = (lo + hi) >> 1; if (batch[mid] < g) lo = mid + 1; else hi = mid; }
    int start = lo;
    lo = start; hi = kN;
    while (lo < hi) { int mid = (lo + hi) >> 1; if (batch[mid] < g + 1) lo = mid + 1; else hi = mid; }
    int end = lo;

    int c = threadIdx.x & 31, r = threadIdx.x >> 5;
    float sum = 0.f, mx = -INFINITY;
    for (int n = start + r; n < end; n += 8) {
        float v = h[n * 32 + c];
        sum += v;
        mx = fmaxf(mx, v);
    }
    __shared__ float ssum[256], smax[256];
    ssum[threadIdx.x] = sum;
    smax[threadIdx.x] = mx;
    __syncthreads();
    if (r == 0) {
#pragma unroll
        for (int i = 1; i < 8; ++i) {
            sum += ssum[i * 32 + c];
            mx = fmaxf(mx, smax[i * 32 + c]);
        }
        int cnt = end - start;
        float mean = sum / fmaxf((float)cnt, 1.f);
        if (cnt <= 0) mx = 0.f;
        gemb[g * 32 + c] = (mean + mx + sum) * (1.f / 3.f);
    }
}

__global__ void k_heads(const float* __restrict__ gemb, const float* __restrict__ ew1,
                        const float* __restrict__ eb1, const float* __restrict__ ew2,
                        const float* __restrict__ eb2, const float* __restrict__ mw1,
                        const float* __restrict__ mb1, const float* __restrict__ mw2,
                        const float* __restrict__ mb2, float* __restrict__ eth,
                        float* __restrict__ man) {
    int g = blockIdx.x * blockDim.x + threadIdx.x;
    if (g >= kG) return;
    const float* row = gemb + g * 32;
    float acc_e = eb2[0], acc_m = mb2[0];
#pragma unroll 4
    for (int j = 0; j < 16; ++j) {
        float he = eb1[j], hm = mb1[j];
        for (int k = 0; k < 32; ++k) {
            float v = row[k];
            he += v * ew1[k * 16 + j];
            hm += v * mw1[k * 16 + j];
        }
        acc_e += fmaxf(he, 0.f) * ew2[j];
        acc_m += fmaxf(hm, 0.f) * mw2[j];
    }
    eth[g] = 1.f / (1.f + expf(-acc_e));
    man[g] = 1.f / (1.f + expf(-acc_m));
}

extern "C" void kernel_launch(void* const* d_in, const int* in_sizes, int n_in,
                              void* d_out, int out_size, void* d_ws, size_t ws_size,
                              hipStream_t stream) {
    const float* x     = (const float*)d_in[0];
    const int*   ei    = (const int*)d_in[1];
    const int*   batch = (const int*)d_in[2];
    const float* enc_w = (const float*)d_in[3];
    const float* enc_b = (const float*)d_in[4];

    float* ws = (float*)d_ws;
    ushort* hcur  = (ushort*)(ws + OFF_HCUR);
    float*  hnext = ws + OFF_HNEXT;
    ushort* z     = (ushort*)(ws + OFF_Z);
    float*  es    = ws + OFF_ES;
    float*  ed    = ws + OFF_ED;
    int*    rowptr= (int*)(ws + OFF_ROWPTR);
    int*    cursor= (int*)(ws + OFF_CURSOR);
    int*    srcc  = (int*)(ws + OFF_SRC);
    ushort* Wt2   = (ushort*)(ws + OFF_WT2);
    float*  ahat  = ws + OFF_AHAT;
    float*  bn    = ws + OFF_BN;
    int*    part  = (int*)(ws + OFF_PART);

    float* out      = (float*)d_out;
    float* out_h    = out;                 // N*32
    float* out_gemb = out + 1600000;       // G*32
    float* out_eth  = out + 1601600;       // G
    float* out_man  = out + 1601650;       // G

    // ---- CSR build (once) ----
    hipMemsetAsync(cursor, 0, kN * sizeof(int), stream);
    k_hist<<<(kET + 255) / 256, 256, 0, stream>>>(ei, cursor);
    k_scan_local<<<kScanBlocks, 1024, 0, stream>>>(cursor, rowptr, part);
    k_scan_part<<<1, 64, 0, stream>>>(part);
    k_scan_add<<<kScanBlocks, 1024, 0, stream>>>(cursor, rowptr, part);
    k_scatter<<<(kET + 255) / 256, 256, 0, stream>>>(ei, cursor, srcc);

    // ---- weight prep for all layers ----
    k_prep_all<<<163, 256, 0, stream>>>((const float*)d_in[5], (const float*)d_in[11],
                                        (const float*)d_in[17], (const float*)d_in[6],
                                        (const float*)d_in[12], (const float*)d_in[18],
                                        (const float*)d_in[7], (const float*)d_in[13],
                                        (const float*)d_in[19], ahat, Wt2);

    // ---- encoder + layer-0 attention terms ----
    k_encoder_att<<<kN / 4, 256, 0, stream>>>(x, enc_w, enc_b, ahat, hcur, es, ed);

    for (int l = 0; l < 3; ++l) {
        const float* gam = (const float*)d_in[9 + 6 * l];
        const float* bet = (const float*)d_in[10 + 6 * l];
        const ushort* Wt2l = Wt2 + l * 16384;

        k_gat<<<kN / 4, 256, 0, stream>>>(rowptr, srcc, es, ed, hcur, z);

        hipMemsetAsync(bn, 0, 2 * 64 * sizeof(float), stream);

        if (l < 2) {
            k_zgemm<64><<<1563, 256, 0, stream>>>(z, Wt2l, hnext);
            k_bn_stats<64><<<128, 256, 0, stream>>>(hnext, bn);
            k_bn_apply_att<<<kN / 4, 256, 0, stream>>>(hnext, bn, gam, bet,
                                                       ahat + (l + 1) * 512, hcur, es, ed);
        } else {
            k_zgemm<32><<<782, 256, 0, stream>>>(z, Wt2l, hnext);
            k_bn_stats<32><<<128, 256, 0, stream>>>(hnext, bn);
            k_bn_apply32<<<(kN * 32 + 255) / 256, 256, 0, stream>>>(hnext, bn, gam, bet, out_h);
        }
    }

    k_pool<<<kG, 256, 0, stream>>>(out_h, batch, out_gemb);

    k_heads<<<1, 64, 0, stream>>>(out_gemb,
                                  (const float*)d_in[23], (const float*)d_in[24],
                                  (const float*)d_in[25], (const float*)d_in[26],
                                  (const float*)d_in[27], (const float*)d_in[28],
                                  (const float*)d_in[29], (const float*)d_in[30],
                                  out_eth, out_man);
}